// Round 5
// baseline (914.202 us; speedup 1.0000x reference)
//
#include <hip/hip_runtime.h>

// HGCNConv on MI355X. Round 5: LDS-tiled VALU GEMM + CSR gather (no atomics
// in aggregation) + fused final chain. Primitive set identical to the
// round-4 PASS (no MFMA builtins, no hip_bf16 API).
//
// ws word layout:
//   [0..95] hyp_bias, [96] ||hb||^2, [97] dtype flag (1=bf16, 0=f32)
//   [128 .. 128+2E)                einfo: uint2 {col, w_bits} per CSR slot
//   then  xt bf16 [N*96 ushorts]   (logmap0 output of HypLinear)
//   then  deg[N] int, off[N+1] int, pos[N] int

#define DIN 256
#define DOUT 96
#define WPAD 264            // W_lds row stride in bf16 elems (256 + 8)
#define MAXN 0.996f         // (1 - 4e-3)/sqrt(c)
#define EPS15 1e-15f
#define ATC (1.0f - 1e-7f)

__device__ __forceinline__ float us2f(unsigned short u) {
    unsigned int v = ((unsigned int)u) << 16;
    return __uint_as_float(v);
}
// float -> bf16 bits, round-to-nearest-even (pure bit ops)
__device__ __forceinline__ unsigned short f2us(float f) {
    unsigned int b = __float_as_uint(f);
    unsigned int r = (b + 0x7FFFu + ((b >> 16) & 1u)) >> 16;
    return (unsigned short)r;
}

// ---- dtype detector (round-4 proven) --------------------------------------
__global__ void detect_kernel(const unsigned short* __restrict__ xraw,
                              float* __restrict__ ws) {
    if (threadIdx.x == 0 && blockIdx.x == 0) {
        int big = 0;
        for (int i = 0; i < 128; i++) {
            float v = us2f(xraw[i]);
            if (!(fabsf(v) < 1e4f)) big = 1;
        }
        ws[97] = big ? 0.0f : 1.0f;
    }
}

// ---- zero int/float words --------------------------------------------------
__global__ void zero_kernel(float* __restrict__ p, long n) {
    long i = (long)blockIdx.x * blockDim.x + threadIdx.x;
    long stride = (long)gridDim.x * blockDim.x;
    for (; i < n; i += stride) p[i] = 0.0f;
}

// ---- hyp_bias = proj(expmap0(bias)) (round-4 proven) ----------------------
__global__ void hb_kernel(const void* __restrict__ bias,
                          float* __restrict__ ws) {
    if (threadIdx.x != 0 || blockIdx.x != 0) return;
    bool isb = ws[97] != 0.0f;
    float b[DOUT];
    float n2 = 0.0f;
    for (int i = 0; i < DOUT; i++) {
        float v = isb ? us2f(((const unsigned short*)bias)[i])
                      : ((const float*)bias)[i];
        b[i] = v;
        n2 += v * v;
    }
    float bn = fmaxf(sqrtf(n2), EPS15);
    float ef = tanhf(bn) / bn;
    float hn = ef * sqrtf(n2);
    float s = (hn > MAXN) ? MAXN / fmaxf(hn, EPS15) : 1.0f;
    for (int i = 0; i < DOUT; i++) ws[i] = s * ef * b[i];
    float v = s * hn;
    ws[96] = v * v;
}

// ---- degree histogram ------------------------------------------------------
__global__ void hist_kernel(const int* __restrict__ erow,
                            int* __restrict__ deg, int E) {
    int e = blockIdx.x * blockDim.x + threadIdx.x;
    if (e < E) atomicAdd(&deg[erow[e]], 1);
}

// ---- exclusive scan over deg -> off, pos (single wave) --------------------
__global__ void scan_kernel(const int* __restrict__ deg,
                            int* __restrict__ off, int* __restrict__ pos,
                            int N) {
    int lane = threadIdx.x;  // 64 threads
    int running = 0;
    for (int base = 0; base < N; base += 64) {
        int i = base + lane;
        int v = (i < N) ? deg[i] : 0;
        int s = v;
        #pragma unroll
        for (int d = 1; d < 64; d <<= 1) {
            int t = __shfl_up(s, d, 64);
            if (lane >= d) s += t;
        }
        int excl = running + s - v;
        if (i < N) { off[i] = excl; pos[i] = excl; }
        running += __shfl(s, 63, 64);
    }
    if (lane == 0) off[N] = running;
}

// ---- CSR fill: einfo[slot] = {col, w_bits} --------------------------------
__global__ void fill_kernel(const void* __restrict__ ew,
                            const int* __restrict__ erow,
                            const int* __restrict__ ecol,
                            float* __restrict__ ws,
                            int* __restrict__ pos,
                            uint2* __restrict__ einfo, int E) {
    int e = blockIdx.x * blockDim.x + threadIdx.x;
    if (e >= E) return;
    const bool isb = ws[97] != 0.0f;
    float w = isb ? us2f(((const unsigned short*)ew)[e]) : ((const float*)ew)[e];
    int p = atomicAdd(&pos[erow[e]], 1);
    uint2 v; v.x = (unsigned)ecol[e]; v.y = __float_as_uint(w);
    einfo[p] = v;
}

// ---- HypLinear v2: LDS-tiled VALU GEMM + mobius tail ----------------------
// Block = 256 (4 waves); 64 rows per block (16 rows per wave, one at a time).
// W staged once in LDS (bf16, padded rows). Per row: x staged fp32 in LDS;
// lane = (col cc = lane>>2, quad q = lane&3) accumulates k in [64q, 64q+64).
__global__ void hyplinear_kernel(const void* __restrict__ x,
                                 const void* __restrict__ wgt,
                                 float* __restrict__ ws,
                                 unsigned short* __restrict__ xtb, int N) {
    __shared__ unsigned short Wl[DOUT * WPAD];  // 50688 B
    __shared__ float xl[4 * DIN];               // 4096 B
    __shared__ float mxl[4 * DOUT];             // 1536 B

    const int t = threadIdx.x;
    const int lane = t & 63;
    const int wv = t >> 6;
    const bool isb = ws[97] != 0.0f;

    // stage W: 96x256 bf16 -> Wl[c*WPAD + k], coalesced ushort4 chunks
    for (int i = 0; i < 24; i++) {
        int flat4 = t + 256 * i;        // 6144 ushort4 chunks
        int c = flat4 >> 6;             // 64 chunks per row
        int k = (flat4 & 63) * 4;
        ushort4 u4;
        if (isb) {
            u4 = ((const ushort4*)wgt)[flat4];
        } else {
            float4 f = ((const float4*)wgt)[flat4];
            u4.x = f2us(f.x); u4.y = f2us(f.y); u4.z = f2us(f.z); u4.w = f2us(f.w);
        }
        *(ushort4*)&Wl[c * WPAD + k] = u4;
    }
    __syncthreads();

    // hb for this lane's cols (constant across rows)
    const float hb0 = ws[lane];
    const float hb1 = (lane < 32) ? ws[64 + lane] : 0.0f;
    const float hb2 = ws[96];

    const int cc = lane >> 2;       // 0..15
    const int q  = lane & 3;        // 0..3
    const int k0 = q * 64;

    for (int rr = 0; rr < 16; rr++) {
        int row = blockIdx.x * 64 + wv * 16 + rr;
        int rowc = (row < N) ? row : (N - 1);

        // stage x row as fp32; compute ||x||^2 via butterfly
        float xf[4];
        if (isb) {
            ushort4 u = *(const ushort4*)((const unsigned short*)x + (size_t)rowc * DIN + lane * 4);
            xf[0] = us2f(u.x); xf[1] = us2f(u.y); xf[2] = us2f(u.z); xf[3] = us2f(u.w);
        } else {
            float4 f = *(const float4*)((const float*)x + (size_t)rowc * DIN + lane * 4);
            xf[0] = f.x; xf[1] = f.y; xf[2] = f.z; xf[3] = f.w;
        }
        float xn2 = xf[0]*xf[0] + xf[1]*xf[1] + xf[2]*xf[2] + xf[3]*xf[3];
        #pragma unroll
        for (int m = 32; m >= 1; m >>= 1) xn2 += __shfl_xor(xn2, m, 64);
        *(float4*)&xl[wv * DIN + lane * 4] = make_float4(xf[0], xf[1], xf[2], xf[3]);
        __syncthreads();

        // 96 dots: 6 col-tiles of 16
        #pragma unroll
        for (int it = 0; it < 6; it++) {
            int c = it * 16 + cc;
            float acc = 0.0f;
            #pragma unroll
            for (int j4 = 0; j4 < 16; j4++) {
                float4 xv = *(const float4*)&xl[wv * DIN + k0 + j4 * 4];
                ushort4 w4 = *(const ushort4*)&Wl[c * WPAD + k0 + j4 * 4];
                acc = fmaf(xv.x, us2f(w4.x), acc);
                acc = fmaf(xv.y, us2f(w4.y), acc);
                acc = fmaf(xv.z, us2f(w4.z), acc);
                acc = fmaf(xv.w, us2f(w4.w), acc);
            }
            acc += __shfl_xor(acc, 1, 64);
            acc += __shfl_xor(acc, 2, 64);
            if (q == 0) mxl[wv * DOUT + c] = acc;
        }
        __syncthreads();

        float mx0 = mxl[wv * DOUT + lane];
        float mx1 = (lane < 32) ? mxl[wv * DOUT + 64 + lane] : 0.0f;

        // row reductions: ||mx||^2 and mx.hb
        float mxn2 = mx0 * mx0 + mx1 * mx1;
        float dmh  = mx0 * hb0 + mx1 * hb1;
        #pragma unroll
        for (int m = 32; m >= 1; m >>= 1) {
            mxn2 += __shfl_xor(mxn2, m, 64);
            dmh  += __shfl_xor(dmh,  m, 64);
        }

        // scalar mobius chain (round-4 proven)
        float xn  = fmaxf(sqrtf(xn2), EPS15);
        float mxn = fmaxf(sqrtf(mxn2), EPS15);
        float g   = (mxn / xn) * atanhf(fminf(xn, ATC));
        float tg  = tanhf(g);
        float rs0 = tg / mxn;
        float rn  = rs0 * sqrtf(mxn2);
        float s1  = (rn > MAXN) ? MAXN / fmaxf(rn, EPS15) : 1.0f;
        float al  = s1 * rs0;
        float x2  = al * al * mxn2;
        float xy  = al * dmh;
        float cA  = 1.0f + 2.0f * xy + hb2;
        float cB  = 1.0f - x2;
        float den = fmaxf(1.0f + 2.0f * xy + x2 * hb2, EPS15);
        float p   = cA * al / den;
        float qq  = cB / den;
        float o2  = p*p*mxn2 + 2.0f*p*qq*dmh + qq*qq*hb2;
        float on  = sqrtf(fmaxf(o2, 0.0f));
        float s2  = (on > MAXN) ? MAXN / fmaxf(on, EPS15) : 1.0f;
        float pn  = fmaxf(s2 * on, EPS15);
        float F   = (atanhf(fminf(pn, ATC)) / pn) * s2;
        float Fp  = F * p, Fq = F * qq;

        if (row < N) {
            size_t ob = (size_t)row * DOUT;
            xtb[ob + lane] = f2us(fmaf(Fp, mx0, Fq * hb0));
            if (lane < 32)
                xtb[ob + 64 + lane] = f2us(fmaf(Fp, mx1, Fq * hb1));
        }
    }
}

// ---- aggregation (CSR gather, no atomics) + fused final chain -------------
__global__ void agg_kernel(const unsigned short* __restrict__ xtb,
                           const uint2* __restrict__ einfo,
                           const int* __restrict__ off,
                           float* __restrict__ ws,
                           void* __restrict__ out, int N) {
    int wv = threadIdx.x >> 6, lane = threadIdx.x & 63;
    int node = blockIdx.x * 4 + wv;
    if (node >= N) return;
    const bool isb = ws[97] != 0.0f;

    int s = off[node], e2 = off[node + 1];
    float acc0 = 0.0f, acc1 = 0.0f;
    for (int j = s; j < e2; j++) {
        uint2 ei = einfo[j];
        int col = (int)ei.x;
        float w = __uint_as_float(ei.y);
        const unsigned short* src = xtb + (size_t)col * DOUT;
        acc0 = fmaf(w, us2f(src[lane]), acc0);
        if (lane < 32) acc1 = fmaf(w, us2f(src[64 + lane]), acc1);
    }

    // proj(expmap0(relu(logmap0(proj(expmap0(support)))))) (round-4 proven)
    float u0 = acc0, u1 = acc1;
    float n2 = u0*u0 + u1*u1;
    #pragma unroll
    for (int m = 32; m >= 1; m >>= 1) n2 += __shfl_xor(n2, m, 64);
    float un = fmaxf(sqrtf(n2), EPS15);
    float ef = tanhf(un) / un;
    float p0 = ef * u0, p1 = ef * u1;
    float pnrm = ef * sqrtf(n2);
    float sc = (pnrm > MAXN) ? MAXN / fmaxf(pnrm, EPS15) : 1.0f;
    p0 *= sc; p1 *= sc; pnrm *= sc;
    float pncl = fmaxf(pnrm, EPS15);
    float lf = atanhf(fminf(pncl, ATC)) / pncl;
    float t0 = fmaxf(lf * p0, 0.0f), t1 = fmaxf(lf * p1, 0.0f);
    float tn2 = t0*t0 + t1*t1;
    #pragma unroll
    for (int m = 32; m >= 1; m >>= 1) tn2 += __shfl_xor(tn2, m, 64);
    float tn = fmaxf(sqrtf(tn2), EPS15);
    float ef2 = tanhf(tn) / tn;
    float en = ef2 * sqrtf(tn2);
    float s2 = (en > MAXN) ? MAXN / fmaxf(en, EPS15) : 1.0f;
    float scale = s2 * ef2;

    size_t ob = (size_t)node * DOUT;
    if (isb) {
        ((unsigned short*)out)[ob + lane] = f2us(scale * t0);
        if (lane < 32)
            ((unsigned short*)out)[ob + 64 + lane] = f2us(scale * t1);
    } else {
        ((float*)out)[ob + lane] = scale * t0;
        if (lane < 32)
            ((float*)out)[ob + 64 + lane] = scale * t1;
    }
}

extern "C" void kernel_launch(void* const* d_in, const int* in_sizes, int n_in,
                              void* d_out, int out_size, void* d_ws, size_t ws_size,
                              hipStream_t stream) {
    const void* x    = d_in[0];
    const void* wgt  = d_in[1];
    const void* bias = d_in[2];
    const void* ew   = d_in[3];
    const int* erow  = (const int*)d_in[4];
    const int* ecol  = (const int*)d_in[5];

    int N = out_size / DOUT;      // 50000
    int E = in_sizes[4];          // 800000
    size_t nd = (size_t)N * DOUT;

    float* wsf = (float*)d_ws;
    uint2* einfo        = (uint2*)(wsf + 128);
    unsigned short* xtb = (unsigned short*)(wsf + 128 + 2 * (size_t)E);
    int* deg            = (int*)(xtb + nd);
    int* off            = deg + N;
    int* pos            = off + N + 1;

    detect_kernel<<<1, 64, 0, stream>>>((const unsigned short*)x, wsf);
    zero_kernel<<<128, 256, 0, stream>>>((float*)deg, N);
    hb_kernel<<<1, 64, 0, stream>>>(bias, wsf);
    hist_kernel<<<(E + 255) / 256, 256, 0, stream>>>(erow, deg, E);
    scan_kernel<<<1, 64, 0, stream>>>(deg, off, pos, N);
    fill_kernel<<<(E + 255) / 256, 256, 0, stream>>>(ew, erow, ecol, wsf, pos, einfo, E);
    hyplinear_kernel<<<(N + 63) / 64, 256, 0, stream>>>(x, wgt, wsf, xtb, N);
    agg_kernel<<<(N + 3) / 4, 256, 0, stream>>>(xtb, einfo, off, wsf, d_out, N);
}

// Round 6
// 537.512 us; speedup vs baseline: 1.7008x; 1.7008x over previous
//
#include <hip/hip_runtime.h>

// HGCNConv on MI355X. Round 6: round-5 pipeline with the serial scan replaced
// by a 3-phase hierarchical scan (the 384us single-wave scan was the top
// dispatch; everything else is unchanged from the round-5 PASS).
//
// ws word layout:
//   [0..95] hyp_bias, [96] ||hb||^2, [97] dtype flag (1=bf16, 0=f32)
//   [128 .. 128+2E)                einfo: uint2 {col, w_bits} per CSR slot
//   then  xt bf16 [N*96 ushorts]   (logmap0 output of HypLinear)
//   then  deg[N] int, off[N+1] int, pos[N] int, bsum[64], boff[64]

#define DIN 256
#define DOUT 96
#define WPAD 264            // W_lds row stride in bf16 elems (256 + 8)
#define MAXN 0.996f         // (1 - 4e-3)/sqrt(c)
#define EPS15 1e-15f
#define ATC (1.0f - 1e-7f)

__device__ __forceinline__ float us2f(unsigned short u) {
    unsigned int v = ((unsigned int)u) << 16;
    return __uint_as_float(v);
}
// float -> bf16 bits, round-to-nearest-even (pure bit ops)
__device__ __forceinline__ unsigned short f2us(float f) {
    unsigned int b = __float_as_uint(f);
    unsigned int r = (b + 0x7FFFu + ((b >> 16) & 1u)) >> 16;
    return (unsigned short)r;
}

// ---- dtype detector (round-4 proven) --------------------------------------
__global__ void detect_kernel(const unsigned short* __restrict__ xraw,
                              float* __restrict__ ws) {
    if (threadIdx.x == 0 && blockIdx.x == 0) {
        int big = 0;
        for (int i = 0; i < 128; i++) {
            float v = us2f(xraw[i]);
            if (!(fabsf(v) < 1e4f)) big = 1;
        }
        ws[97] = big ? 0.0f : 1.0f;
    }
}

// ---- zero int/float words --------------------------------------------------
__global__ void zero_kernel(float* __restrict__ p, long n) {
    long i = (long)blockIdx.x * blockDim.x + threadIdx.x;
    long stride = (long)gridDim.x * blockDim.x;
    for (; i < n; i += stride) p[i] = 0.0f;
}

// ---- hyp_bias = proj(expmap0(bias)) (round-4 proven) ----------------------
__global__ void hb_kernel(const void* __restrict__ bias,
                          float* __restrict__ ws) {
    if (threadIdx.x != 0 || blockIdx.x != 0) return;
    bool isb = ws[97] != 0.0f;
    float b[DOUT];
    float n2 = 0.0f;
    for (int i = 0; i < DOUT; i++) {
        float v = isb ? us2f(((const unsigned short*)bias)[i])
                      : ((const float*)bias)[i];
        b[i] = v;
        n2 += v * v;
    }
    float bn = fmaxf(sqrtf(n2), EPS15);
    float ef = tanhf(bn) / bn;
    float hn = ef * sqrtf(n2);
    float s = (hn > MAXN) ? MAXN / fmaxf(hn, EPS15) : 1.0f;
    for (int i = 0; i < DOUT; i++) ws[i] = s * ef * b[i];
    float v = s * hn;
    ws[96] = v * v;
}

// ---- degree histogram ------------------------------------------------------
__global__ void hist_kernel(const int* __restrict__ erow,
                            int* __restrict__ deg, int E) {
    int e = blockIdx.x * blockDim.x + threadIdx.x;
    if (e < E) atomicAdd(&deg[erow[e]], 1);
}

// ---- hierarchical scan: phase A (per-block sums of 1024 elems) ------------
__global__ void scanA_kernel(const int* __restrict__ deg,
                             int* __restrict__ bsum, int N) {
    int t = threadIdx.x, lane = t & 63, wv = t >> 6;
    int base = blockIdx.x * 1024 + t * 4;
    int v = 0;
    #pragma unroll
    for (int j = 0; j < 4; j++) {
        int i = base + j;
        if (i < N) v += deg[i];
    }
    #pragma unroll
    for (int m = 32; m >= 1; m >>= 1) v += __shfl_xor(v, m, 64);
    __shared__ int wsum[4];
    if (lane == 0) wsum[wv] = v;
    __syncthreads();
    if (t == 0) bsum[blockIdx.x] = wsum[0] + wsum[1] + wsum[2] + wsum[3];
}

// ---- phase B: one wave scans the block sums -------------------------------
__global__ void scanB_kernel(const int* __restrict__ bsum,
                             int* __restrict__ boff,
                             int* __restrict__ offN, int nb) {
    int lane = threadIdx.x;  // 64 threads
    int running = 0;
    for (int b = 0; b < nb; b += 64) {
        int i = b + lane;
        int v = (i < nb) ? bsum[i] : 0;
        int s = v;
        #pragma unroll
        for (int d = 1; d < 64; d <<= 1) {
            int t = __shfl_up(s, d, 64);
            if (lane >= d) s += t;
        }
        if (i < nb) boff[i] = running + s - v;
        running += __shfl(s, 63, 64);
    }
    if (lane == 0) *offN = running;
}

// ---- phase C: block-local exclusive scan + block offset -------------------
__global__ void scanC_kernel(const int* __restrict__ deg,
                             const int* __restrict__ boff,
                             int* __restrict__ off, int* __restrict__ pos,
                             int N) {
    int t = threadIdx.x, lane = t & 63, wv = t >> 6;
    int base = blockIdx.x * 1024 + t * 4;
    int v[4]; int s = 0;
    #pragma unroll
    for (int j = 0; j < 4; j++) {
        int i = base + j;
        v[j] = (i < N) ? deg[i] : 0;
        s += v[j];
    }
    int sc = s;
    #pragma unroll
    for (int d = 1; d < 64; d <<= 1) {
        int tt = __shfl_up(sc, d, 64);
        if (lane >= d) sc += tt;
    }
    __shared__ int wsum[4];
    if (lane == 63) wsum[wv] = sc;
    __syncthreads();
    int wo = 0;
    for (int k = 0; k < wv; k++) wo += wsum[k];
    int excl = boff[blockIdx.x] + wo + (sc - s);
    #pragma unroll
    for (int j = 0; j < 4; j++) {
        int i = base + j;
        if (i < N) { off[i] = excl; pos[i] = excl; }
        excl += v[j];
    }
}

// ---- CSR fill: einfo[slot] = {col, w_bits} --------------------------------
__global__ void fill_kernel(const void* __restrict__ ew,
                            const int* __restrict__ erow,
                            const int* __restrict__ ecol,
                            float* __restrict__ ws,
                            int* __restrict__ pos,
                            uint2* __restrict__ einfo, int E) {
    int e = blockIdx.x * blockDim.x + threadIdx.x;
    if (e >= E) return;
    const bool isb = ws[97] != 0.0f;
    float w = isb ? us2f(((const unsigned short*)ew)[e]) : ((const float*)ew)[e];
    int p = atomicAdd(&pos[erow[e]], 1);
    uint2 v; v.x = (unsigned)ecol[e]; v.y = __float_as_uint(w);
    einfo[p] = v;
}

// ---- HypLinear v2: LDS-tiled VALU GEMM + mobius tail (round-5 proven) -----
__global__ void hyplinear_kernel(const void* __restrict__ x,
                                 const void* __restrict__ wgt,
                                 float* __restrict__ ws,
                                 unsigned short* __restrict__ xtb, int N) {
    __shared__ unsigned short Wl[DOUT * WPAD];  // 50688 B
    __shared__ float xl[4 * DIN];               // 4096 B
    __shared__ float mxl[4 * DOUT];             // 1536 B

    const int t = threadIdx.x;
    const int lane = t & 63;
    const int wv = t >> 6;
    const bool isb = ws[97] != 0.0f;

    // stage W: 96x256 bf16 -> Wl[c*WPAD + k], coalesced ushort4 chunks
    for (int i = 0; i < 24; i++) {
        int flat4 = t + 256 * i;        // 6144 ushort4 chunks
        int c = flat4 >> 6;             // 64 chunks per row
        int k = (flat4 & 63) * 4;
        ushort4 u4;
        if (isb) {
            u4 = ((const ushort4*)wgt)[flat4];
        } else {
            float4 f = ((const float4*)wgt)[flat4];
            u4.x = f2us(f.x); u4.y = f2us(f.y); u4.z = f2us(f.z); u4.w = f2us(f.w);
        }
        *(ushort4*)&Wl[c * WPAD + k] = u4;
    }
    __syncthreads();

    const float hb0 = ws[lane];
    const float hb1 = (lane < 32) ? ws[64 + lane] : 0.0f;
    const float hb2 = ws[96];

    const int cc = lane >> 2;       // 0..15
    const int q  = lane & 3;        // 0..3
    const int k0 = q * 64;

    for (int rr = 0; rr < 16; rr++) {
        int row = blockIdx.x * 64 + wv * 16 + rr;
        int rowc = (row < N) ? row : (N - 1);

        float xf[4];
        if (isb) {
            ushort4 u = *(const ushort4*)((const unsigned short*)x + (size_t)rowc * DIN + lane * 4);
            xf[0] = us2f(u.x); xf[1] = us2f(u.y); xf[2] = us2f(u.z); xf[3] = us2f(u.w);
        } else {
            float4 f = *(const float4*)((const float*)x + (size_t)rowc * DIN + lane * 4);
            xf[0] = f.x; xf[1] = f.y; xf[2] = f.z; xf[3] = f.w;
        }
        float xn2 = xf[0]*xf[0] + xf[1]*xf[1] + xf[2]*xf[2] + xf[3]*xf[3];
        #pragma unroll
        for (int m = 32; m >= 1; m >>= 1) xn2 += __shfl_xor(xn2, m, 64);
        *(float4*)&xl[wv * DIN + lane * 4] = make_float4(xf[0], xf[1], xf[2], xf[3]);
        __syncthreads();

        #pragma unroll
        for (int it = 0; it < 6; it++) {
            int c = it * 16 + cc;
            float acc = 0.0f;
            #pragma unroll
            for (int j4 = 0; j4 < 16; j4++) {
                float4 xv = *(const float4*)&xl[wv * DIN + k0 + j4 * 4];
                ushort4 w4 = *(const ushort4*)&Wl[c * WPAD + k0 + j4 * 4];
                acc = fmaf(xv.x, us2f(w4.x), acc);
                acc = fmaf(xv.y, us2f(w4.y), acc);
                acc = fmaf(xv.z, us2f(w4.z), acc);
                acc = fmaf(xv.w, us2f(w4.w), acc);
            }
            acc += __shfl_xor(acc, 1, 64);
            acc += __shfl_xor(acc, 2, 64);
            if (q == 0) mxl[wv * DOUT + c] = acc;
        }
        __syncthreads();

        float mx0 = mxl[wv * DOUT + lane];
        float mx1 = (lane < 32) ? mxl[wv * DOUT + 64 + lane] : 0.0f;

        float mxn2 = mx0 * mx0 + mx1 * mx1;
        float dmh  = mx0 * hb0 + mx1 * hb1;
        #pragma unroll
        for (int m = 32; m >= 1; m >>= 1) {
            mxn2 += __shfl_xor(mxn2, m, 64);
            dmh  += __shfl_xor(dmh,  m, 64);
        }

        float xn  = fmaxf(sqrtf(xn2), EPS15);
        float mxn = fmaxf(sqrtf(mxn2), EPS15);
        float g   = (mxn / xn) * atanhf(fminf(xn, ATC));
        float tg  = tanhf(g);
        float rs0 = tg / mxn;
        float rn  = rs0 * sqrtf(mxn2);
        float s1  = (rn > MAXN) ? MAXN / fmaxf(rn, EPS15) : 1.0f;
        float al  = s1 * rs0;
        float x2  = al * al * mxn2;
        float xy  = al * dmh;
        float cA  = 1.0f + 2.0f * xy + hb2;
        float cB  = 1.0f - x2;
        float den = fmaxf(1.0f + 2.0f * xy + x2 * hb2, EPS15);
        float p   = cA * al / den;
        float qq  = cB / den;
        float o2  = p*p*mxn2 + 2.0f*p*qq*dmh + qq*qq*hb2;
        float on  = sqrtf(fmaxf(o2, 0.0f));
        float s2  = (on > MAXN) ? MAXN / fmaxf(on, EPS15) : 1.0f;
        float pn  = fmaxf(s2 * on, EPS15);
        float F   = (atanhf(fminf(pn, ATC)) / pn) * s2;
        float Fp  = F * p, Fq = F * qq;

        if (row < N) {
            size_t ob = (size_t)row * DOUT;
            xtb[ob + lane] = f2us(fmaf(Fp, mx0, Fq * hb0));
            if (lane < 32)
                xtb[ob + 64 + lane] = f2us(fmaf(Fp, mx1, Fq * hb1));
        }
    }
}

// ---- aggregation (CSR gather, no atomics) + fused final chain -------------
__global__ void agg_kernel(const unsigned short* __restrict__ xtb,
                           const uint2* __restrict__ einfo,
                           const int* __restrict__ off,
                           float* __restrict__ ws,
                           void* __restrict__ out, int N) {
    int wv = threadIdx.x >> 6, lane = threadIdx.x & 63;
    int node = blockIdx.x * 4 + wv;
    if (node >= N) return;
    const bool isb = ws[97] != 0.0f;

    int s = off[node], e2 = off[node + 1];
    float acc0 = 0.0f, acc1 = 0.0f;
    for (int j = s; j < e2; j++) {
        uint2 ei = einfo[j];
        int col = (int)ei.x;
        float w = __uint_as_float(ei.y);
        const unsigned short* src = xtb + (size_t)col * DOUT;
        acc0 = fmaf(w, us2f(src[lane]), acc0);
        if (lane < 32) acc1 = fmaf(w, us2f(src[64 + lane]), acc1);
    }

    float u0 = acc0, u1 = acc1;
    float n2 = u0*u0 + u1*u1;
    #pragma unroll
    for (int m = 32; m >= 1; m >>= 1) n2 += __shfl_xor(n2, m, 64);
    float un = fmaxf(sqrtf(n2), EPS15);
    float ef = tanhf(un) / un;
    float p0 = ef * u0, p1 = ef * u1;
    float pnrm = ef * sqrtf(n2);
    float sc = (pnrm > MAXN) ? MAXN / fmaxf(pnrm, EPS15) : 1.0f;
    p0 *= sc; p1 *= sc; pnrm *= sc;
    float pncl = fmaxf(pnrm, EPS15);
    float lf = atanhf(fminf(pncl, ATC)) / pncl;
    float t0 = fmaxf(lf * p0, 0.0f), t1 = fmaxf(lf * p1, 0.0f);
    float tn2 = t0*t0 + t1*t1;
    #pragma unroll
    for (int m = 32; m >= 1; m >>= 1) tn2 += __shfl_xor(tn2, m, 64);
    float tn = fmaxf(sqrtf(tn2), EPS15);
    float ef2 = tanhf(tn) / tn;
    float en = ef2 * sqrtf(tn2);
    float s2 = (en > MAXN) ? MAXN / fmaxf(en, EPS15) : 1.0f;
    float scale = s2 * ef2;

    size_t ob = (size_t)node * DOUT;
    if (isb) {
        ((unsigned short*)out)[ob + lane] = f2us(scale * t0);
        if (lane < 32)
            ((unsigned short*)out)[ob + 64 + lane] = f2us(scale * t1);
    } else {
        ((float*)out)[ob + lane] = scale * t0;
        if (lane < 32)
            ((float*)out)[ob + 64 + lane] = scale * t1;
    }
}

extern "C" void kernel_launch(void* const* d_in, const int* in_sizes, int n_in,
                              void* d_out, int out_size, void* d_ws, size_t ws_size,
                              hipStream_t stream) {
    const void* x    = d_in[0];
    const void* wgt  = d_in[1];
    const void* bias = d_in[2];
    const void* ew   = d_in[3];
    const int* erow  = (const int*)d_in[4];
    const int* ecol  = (const int*)d_in[5];

    int N = out_size / DOUT;      // 50000
    int E = in_sizes[4];          // 800000
    size_t nd = (size_t)N * DOUT;
    int nb = (N + 1023) / 1024;   // scan blocks (49)

    float* wsf = (float*)d_ws;
    uint2* einfo        = (uint2*)(wsf + 128);
    unsigned short* xtb = (unsigned short*)(wsf + 128 + 2 * (size_t)E);
    int* deg            = (int*)(xtb + nd);
    int* off            = deg + N;
    int* pos            = off + N + 1;
    int* bsum           = pos + N;
    int* boff           = bsum + 64;

    detect_kernel<<<1, 64, 0, stream>>>((const unsigned short*)x, wsf);
    zero_kernel<<<128, 256, 0, stream>>>((float*)deg, N);
    hb_kernel<<<1, 64, 0, stream>>>(bias, wsf);
    hist_kernel<<<(E + 255) / 256, 256, 0, stream>>>(erow, deg, E);
    scanA_kernel<<<nb, 256, 0, stream>>>(deg, bsum, N);
    scanB_kernel<<<1, 64, 0, stream>>>(bsum, boff, off + N, nb);
    scanC_kernel<<<nb, 256, 0, stream>>>(deg, boff, off, pos, N);
    fill_kernel<<<(E + 255) / 256, 256, 0, stream>>>(ew, erow, ecol, wsf, pos, einfo, E);
    hyplinear_kernel<<<(N + 63) / 64, 256, 0, stream>>>(x, wgt, wsf, xtb, N);
    agg_kernel<<<(N + 3) / 4, 256, 0, stream>>>(xtb, einfo, off, wsf, d_out, N);
}

// Round 7
// 328.364 us; speedup vs baseline: 2.7841x; 1.6369x over previous
//
#include <hip/hip_runtime.h>

// HGCNConv on MI355X. Round 7: round-6 pipeline with hyplinear swapped to
// MFMA (guide-verified short8 fragment form, no __launch_bounds__).
// Everything else byte-identical to the round-6 PASS.
//
// ws word layout:
//   [0..95] hyp_bias, [96] ||hb||^2, [97] dtype flag (1=bf16, 0=f32)
//   [128 .. 128+2E)                einfo: uint2 {col, w_bits} per CSR slot
//   then  xt bf16 [N*96 ushorts]   (logmap0 output of HypLinear)
//   then  deg[N] int, off[N+1] int, pos[N] int, bsum[64], boff[64]

typedef __attribute__((ext_vector_type(8))) short short8;
typedef __attribute__((ext_vector_type(4))) float floatx4;

#define DIN 256
#define DOUT 96
#define MAXN 0.996f         // (1 - 4e-3)/sqrt(c)
#define EPS15 1e-15f
#define ATC (1.0f - 1e-7f)

__device__ __forceinline__ float us2f(unsigned short u) {
    unsigned int v = ((unsigned int)u) << 16;
    return __uint_as_float(v);
}
// float -> bf16 bits, round-to-nearest-even (pure bit ops)
__device__ __forceinline__ unsigned short f2us(float f) {
    unsigned int b = __float_as_uint(f);
    unsigned int r = (b + 0x7FFFu + ((b >> 16) & 1u)) >> 16;
    return (unsigned short)r;
}

// ---- dtype detector (round-4 proven) --------------------------------------
__global__ void detect_kernel(const unsigned short* __restrict__ xraw,
                              float* __restrict__ ws) {
    if (threadIdx.x == 0 && blockIdx.x == 0) {
        int big = 0;
        for (int i = 0; i < 128; i++) {
            float v = us2f(xraw[i]);
            if (!(fabsf(v) < 1e4f)) big = 1;
        }
        ws[97] = big ? 0.0f : 1.0f;
    }
}

// ---- zero int/float words --------------------------------------------------
__global__ void zero_kernel(float* __restrict__ p, long n) {
    long i = (long)blockIdx.x * blockDim.x + threadIdx.x;
    long stride = (long)gridDim.x * blockDim.x;
    for (; i < n; i += stride) p[i] = 0.0f;
}

// ---- hyp_bias = proj(expmap0(bias)) (round-4 proven) ----------------------
__global__ void hb_kernel(const void* __restrict__ bias,
                          float* __restrict__ ws) {
    if (threadIdx.x != 0 || blockIdx.x != 0) return;
    bool isb = ws[97] != 0.0f;
    float b[DOUT];
    float n2 = 0.0f;
    for (int i = 0; i < DOUT; i++) {
        float v = isb ? us2f(((const unsigned short*)bias)[i])
                      : ((const float*)bias)[i];
        b[i] = v;
        n2 += v * v;
    }
    float bn = fmaxf(sqrtf(n2), EPS15);
    float ef = tanhf(bn) / bn;
    float hn = ef * sqrtf(n2);
    float s = (hn > MAXN) ? MAXN / fmaxf(hn, EPS15) : 1.0f;
    for (int i = 0; i < DOUT; i++) ws[i] = s * ef * b[i];
    float v = s * hn;
    ws[96] = v * v;
}

// ---- degree histogram ------------------------------------------------------
__global__ void hist_kernel(const int* __restrict__ erow,
                            int* __restrict__ deg, int E) {
    int e = blockIdx.x * blockDim.x + threadIdx.x;
    if (e < E) atomicAdd(&deg[erow[e]], 1);
}

// ---- hierarchical scan: phase A (per-block sums of 1024 elems) ------------
__global__ void scanA_kernel(const int* __restrict__ deg,
                             int* __restrict__ bsum, int N) {
    int t = threadIdx.x, lane = t & 63, wv = t >> 6;
    int base = blockIdx.x * 1024 + t * 4;
    int v = 0;
    #pragma unroll
    for (int j = 0; j < 4; j++) {
        int i = base + j;
        if (i < N) v += deg[i];
    }
    #pragma unroll
    for (int m = 32; m >= 1; m >>= 1) v += __shfl_xor(v, m, 64);
    __shared__ int wsum[4];
    if (lane == 0) wsum[wv] = v;
    __syncthreads();
    if (t == 0) bsum[blockIdx.x] = wsum[0] + wsum[1] + wsum[2] + wsum[3];
}

// ---- phase B: one wave scans the block sums -------------------------------
__global__ void scanB_kernel(const int* __restrict__ bsum,
                             int* __restrict__ boff,
                             int* __restrict__ offN, int nb) {
    int lane = threadIdx.x;  // 64 threads
    int running = 0;
    for (int b = 0; b < nb; b += 64) {
        int i = b + lane;
        int v = (i < nb) ? bsum[i] : 0;
        int s = v;
        #pragma unroll
        for (int d = 1; d < 64; d <<= 1) {
            int t = __shfl_up(s, d, 64);
            if (lane >= d) s += t;
        }
        if (i < nb) boff[i] = running + s - v;
        running += __shfl(s, 63, 64);
    }
    if (lane == 0) *offN = running;
}

// ---- phase C: block-local exclusive scan + block offset -------------------
__global__ void scanC_kernel(const int* __restrict__ deg,
                             const int* __restrict__ boff,
                             int* __restrict__ off, int* __restrict__ pos,
                             int N) {
    int t = threadIdx.x, lane = t & 63, wv = t >> 6;
    int base = blockIdx.x * 1024 + t * 4;
    int v[4]; int s = 0;
    #pragma unroll
    for (int j = 0; j < 4; j++) {
        int i = base + j;
        v[j] = (i < N) ? deg[i] : 0;
        s += v[j];
    }
    int sc = s;
    #pragma unroll
    for (int d = 1; d < 64; d <<= 1) {
        int tt = __shfl_up(sc, d, 64);
        if (lane >= d) sc += tt;
    }
    __shared__ int wsum[4];
    if (lane == 63) wsum[wv] = sc;
    __syncthreads();
    int wo = 0;
    for (int k = 0; k < wv; k++) wo += wsum[k];
    int excl = boff[blockIdx.x] + wo + (sc - s);
    #pragma unroll
    for (int j = 0; j < 4; j++) {
        int i = base + j;
        if (i < N) { off[i] = excl; pos[i] = excl; }
        excl += v[j];
    }
}

// ---- CSR fill: einfo[slot] = {col, w_bits} --------------------------------
__global__ void fill_kernel(const void* __restrict__ ew,
                            const int* __restrict__ erow,
                            const int* __restrict__ ecol,
                            float* __restrict__ ws,
                            int* __restrict__ pos,
                            uint2* __restrict__ einfo, int E) {
    int e = blockIdx.x * blockDim.x + threadIdx.x;
    if (e >= E) return;
    const bool isb = ws[97] != 0.0f;
    float w = isb ? us2f(((const unsigned short*)ew)[e]) : ((const float*)ew)[e];
    int p = atomicAdd(&pos[erow[e]], 1);
    uint2 v; v.x = (unsigned)ecol[e]; v.y = __float_as_uint(w);
    einfo[p] = v;
}

// ---- HypLinear v3: MFMA GEMM + scalar mobius tail -------------------------
// One wave = 16 rows x 96 cols, fragments loaded straight from global.
// 48 MFMAs per wave; no LDS.
__global__ void hyplinear_kernel(const void* __restrict__ x,
                                 const void* __restrict__ wgt,
                                 float* __restrict__ ws,
                                 unsigned short* __restrict__ xtb, int N) {
    const int lane = threadIdx.x & 63;
    const int wv = threadIdx.x >> 6;
    const int mrow = lane & 15;
    const int quad = lane >> 4;
    const int r0 = (blockIdx.x * 4 + wv) * 16;
    if (r0 >= N) return;
    const bool isb = ws[97] != 0.0f;

    // hb values for this lane's columns (col = mrow + 16f), plus ||hb||^2
    float hbl[6];
    #pragma unroll
    for (int f = 0; f < 6; f++) hbl[f] = ws[mrow + 16 * f];
    const float hb2 = ws[96];

    // A fragments: x row (r0+mrow), k = quad*8 + kt*32 + [0..7]
    int xr = r0 + mrow; if (xr >= N) xr = N - 1;
    short8 afrag[8];
    if (isb) {
        const unsigned short* xrow = (const unsigned short*)x + (size_t)xr * DIN + quad * 8;
        #pragma unroll
        for (int kt = 0; kt < 8; kt++)
            afrag[kt] = *(const short8*)(xrow + kt * 32);
    } else {
        const float* xrow = (const float*)x + (size_t)xr * DIN + quad * 8;
        #pragma unroll
        for (int kt = 0; kt < 8; kt++) {
            short8 a;
            #pragma unroll
            for (int j = 0; j < 8; j++) a[j] = (short)f2us(xrow[kt * 32 + j]);
            afrag[kt] = a;
        }
    }

    // ||x_row||^2 : each lane holds 64 of the 256 elems of row mrow
    float xn2p = 0.f;
    #pragma unroll
    for (int kt = 0; kt < 8; kt++)
        #pragma unroll
        for (int j = 0; j < 8; j++) {
            float v = us2f((unsigned short)afrag[kt][j]);
            xn2p = fmaf(v, v, xn2p);
        }
    xn2p += __shfl_xor(xn2p, 16, 64);
    xn2p += __shfl_xor(xn2p, 32, 64);
    // lane L now holds ||x_{r0 + (L&15)}||^2

    // mx = x @ W^T : 6 col-tiles of 16, K=256 in 8 MFMA steps
    floatx4 acc[6];
    #pragma unroll
    for (int f = 0; f < 6; f++) acc[f] = (floatx4){0.f, 0.f, 0.f, 0.f};
    #pragma unroll
    for (int f = 0; f < 6; f++) {
        if (isb) {
            const unsigned short* wrow = (const unsigned short*)wgt + (size_t)(16 * f + mrow) * DIN + quad * 8;
            #pragma unroll
            for (int kt = 0; kt < 8; kt++) {
                short8 b = *(const short8*)(wrow + kt * 32);
                acc[f] = __builtin_amdgcn_mfma_f32_16x16x32_bf16(afrag[kt], b, acc[f], 0, 0, 0);
            }
        } else {
            const float* wrow = (const float*)wgt + (size_t)(16 * f + mrow) * DIN + quad * 8;
            #pragma unroll
            for (int kt = 0; kt < 8; kt++) {
                short8 b;
                #pragma unroll
                for (int j = 0; j < 8; j++) b[j] = (short)f2us(wrow[kt * 32 + j]);
                acc[f] = __builtin_amdgcn_mfma_f32_16x16x32_bf16(afrag[kt], b, acc[f], 0, 0, 0);
            }
        }
    }
    // D layout (m89-verified): acc[f][reg] = mx[row = quad*4+reg][col = mrow + 16f]

    // per-row reductions over the 96 cols: ||mx||^2 and mx . hb
    float mxn2[4], dmh[4];
    #pragma unroll
    for (int reg = 0; reg < 4; reg++) {
        float a2 = 0.f, ad = 0.f;
        #pragma unroll
        for (int f = 0; f < 6; f++) {
            float v = acc[f][reg];
            a2 = fmaf(v, v, a2);
            ad = fmaf(v, hbl[f], ad);
        }
        mxn2[reg] = a2; dmh[reg] = ad;
    }
    #pragma unroll
    for (int m = 8; m >= 1; m >>= 1)
        #pragma unroll
        for (int reg = 0; reg < 4; reg++) {
            mxn2[reg] += __shfl_xor(mxn2[reg], m, 64);
            dmh[reg]  += __shfl_xor(dmh[reg],  m, 64);
        }

    // scalar mobius chain (round-4/5/6-proven algebra): lane handles
    // reg = mrow & 3 (row quad*4+reg)
    int sel = mrow & 3;
    float xn2  = __shfl(xn2p, quad * 4 + sel, 64);
    float wmx2 = mxn2[sel], wdmh = dmh[sel];

    float xn  = fmaxf(sqrtf(xn2), EPS15);
    float mxn = fmaxf(sqrtf(wmx2), EPS15);
    float g   = (mxn / xn) * atanhf(fminf(xn, ATC));
    float tg  = tanhf(g);
    float rs0 = tg / mxn;
    float rn  = rs0 * sqrtf(wmx2);
    float s1  = (rn > MAXN) ? MAXN / fmaxf(rn, EPS15) : 1.0f;
    float al  = s1 * rs0;
    float x2  = al * al * wmx2;
    float xy  = al * wdmh;
    float cA  = 1.0f + 2.0f * xy + hb2;
    float cB  = 1.0f - x2;
    float den = fmaxf(1.0f + 2.0f * xy + x2 * hb2, EPS15);
    float p   = cA * al / den;
    float qq  = cB / den;
    float o2  = p*p*wmx2 + 2.0f*p*qq*wdmh + qq*qq*hb2;
    float on  = sqrtf(fmaxf(o2, 0.0f));
    float s2  = (on > MAXN) ? MAXN / fmaxf(on, EPS15) : 1.0f;
    float pn  = fmaxf(s2 * on, EPS15);
    float F   = (atanhf(fminf(pn, ATC)) / pn) * s2;
    float Fp_m = F * p, Fq_m = F * qq;

    // broadcast per-reg factors from lane (quad*16 + reg)
    float Fp[4], Fq[4];
    #pragma unroll
    for (int reg = 0; reg < 4; reg++) {
        Fp[reg] = __shfl(Fp_m, quad * 16 + reg, 64);
        Fq[reg] = __shfl(Fq_m, quad * 16 + reg, 64);
    }

    // xt[row][col] = Fp*mx + Fq*hb (bf16)
    #pragma unroll
    for (int reg = 0; reg < 4; reg++) {
        int row = r0 + quad * 4 + reg;
        if (row < N) {
            size_t base = (size_t)row * DOUT + mrow;
            #pragma unroll
            for (int f = 0; f < 6; f++)
                xtb[base + 16 * f] = f2us(fmaf(Fp[reg], acc[f][reg], Fq[reg] * hbl[f]));
        }
    }
}

// ---- aggregation (CSR gather, no atomics) + fused final chain -------------
__global__ void agg_kernel(const unsigned short* __restrict__ xtb,
                           const uint2* __restrict__ einfo,
                           const int* __restrict__ off,
                           float* __restrict__ ws,
                           void* __restrict__ out, int N) {
    int wv = threadIdx.x >> 6, lane = threadIdx.x & 63;
    int node = blockIdx.x * 4 + wv;
    if (node >= N) return;
    const bool isb = ws[97] != 0.0f;

    int s = off[node], e2 = off[node + 1];
    float acc0 = 0.0f, acc1 = 0.0f;
    for (int j = s; j < e2; j++) {
        uint2 ei = einfo[j];
        int col = (int)ei.x;
        float w = __uint_as_float(ei.y);
        const unsigned short* src = xtb + (size_t)col * DOUT;
        acc0 = fmaf(w, us2f(src[lane]), acc0);
        if (lane < 32) acc1 = fmaf(w, us2f(src[64 + lane]), acc1);
    }

    float u0 = acc0, u1 = acc1;
    float n2 = u0*u0 + u1*u1;
    #pragma unroll
    for (int m = 32; m >= 1; m >>= 1) n2 += __shfl_xor(n2, m, 64);
    float un = fmaxf(sqrtf(n2), EPS15);
    float ef = tanhf(un) / un;
    float p0 = ef * u0, p1 = ef * u1;
    float pnrm = ef * sqrtf(n2);
    float sc = (pnrm > MAXN) ? MAXN / fmaxf(pnrm, EPS15) : 1.0f;
    p0 *= sc; p1 *= sc; pnrm *= sc;
    float pncl = fmaxf(pnrm, EPS15);
    float lf = atanhf(fminf(pncl, ATC)) / pncl;
    float t0 = fmaxf(lf * p0, 0.0f), t1 = fmaxf(lf * p1, 0.0f);
    float tn2 = t0*t0 + t1*t1;
    #pragma unroll
    for (int m = 32; m >= 1; m >>= 1) tn2 += __shfl_xor(tn2, m, 64);
    float tn = fmaxf(sqrtf(tn2), EPS15);
    float ef2 = tanhf(tn) / tn;
    float en = ef2 * sqrtf(tn2);
    float s2 = (en > MAXN) ? MAXN / fmaxf(en, EPS15) : 1.0f;
    float scale = s2 * ef2;

    size_t ob = (size_t)node * DOUT;
    if (isb) {
        ((unsigned short*)out)[ob + lane] = f2us(scale * t0);
        if (lane < 32)
            ((unsigned short*)out)[ob + 64 + lane] = f2us(scale * t1);
    } else {
        ((float*)out)[ob + lane] = scale * t0;
        if (lane < 32)
            ((float*)out)[ob + 64 + lane] = scale * t1;
    }
}

extern "C" void kernel_launch(void* const* d_in, const int* in_sizes, int n_in,
                              void* d_out, int out_size, void* d_ws, size_t ws_size,
                              hipStream_t stream) {
    const void* x    = d_in[0];
    const void* wgt  = d_in[1];
    const void* bias = d_in[2];
    const void* ew   = d_in[3];
    const int* erow  = (const int*)d_in[4];
    const int* ecol  = (const int*)d_in[5];

    int N = out_size / DOUT;      // 50000
    int E = in_sizes[4];          // 800000
    size_t nd = (size_t)N * DOUT;
    int nb = (N + 1023) / 1024;   // scan blocks (49)

    float* wsf = (float*)d_ws;
    uint2* einfo        = (uint2*)(wsf + 128);
    unsigned short* xtb = (unsigned short*)(wsf + 128 + 2 * (size_t)E);
    int* deg            = (int*)(xtb + nd);
    int* off            = deg + N;
    int* pos            = off + N + 1;
    int* bsum           = pos + N;
    int* boff           = bsum + 64;

    detect_kernel<<<1, 64, 0, stream>>>((const unsigned short*)x, wsf);
    zero_kernel<<<128, 256, 0, stream>>>((float*)deg, N);
    hb_kernel<<<1, 64, 0, stream>>>(bias, wsf);
    hist_kernel<<<(E + 255) / 256, 256, 0, stream>>>(erow, deg, E);
    scanA_kernel<<<nb, 256, 0, stream>>>(deg, bsum, N);
    scanB_kernel<<<1, 64, 0, stream>>>(bsum, boff, off + N, nb);
    scanC_kernel<<<nb, 256, 0, stream>>>(deg, boff, off, pos, N);
    fill_kernel<<<(E + 255) / 256, 256, 0, stream>>>(ew, erow, ecol, wsf, pos, einfo, E);
    hyplinear_kernel<<<(N + 63) / 64, 256, 0, stream>>>(x, wgt, wsf, xtb, N);
    agg_kernel<<<(N + 3) / 4, 256, 0, stream>>>(xtb, einfo, off, wsf, d_out, N);
}

// Round 8
// 296.408 us; speedup vs baseline: 3.0843x; 1.1078x over previous
//
#include <hip/hip_runtime.h>

// HGCNConv on MI355X. Round 8: round-7 pipeline with (a) agg_kernel given
// coalesced einfo preload + 4-edge unroll (8 gathers in flight), (b) detect
// and hb kernels wave-parallelized (they were serial-thread latency sinks).
// Everything else byte-identical to the round-7 PASS.
//
// ws word layout:
//   [0..95] hyp_bias, [96] ||hb||^2, [97] dtype flag (1=bf16, 0=f32)
//   [128 .. 128+2E)                einfo: uint2 {col, w_bits} per CSR slot
//   then  xt bf16 [N*96 ushorts]   (logmap0 output of HypLinear)
//   then  deg[N] int, off[N+1] int, pos[N] int, bsum[64], boff[64]

typedef __attribute__((ext_vector_type(8))) short short8;
typedef __attribute__((ext_vector_type(4))) float floatx4;

#define DIN 256
#define DOUT 96
#define MAXN 0.996f         // (1 - 4e-3)/sqrt(c)
#define EPS15 1e-15f
#define ATC (1.0f - 1e-7f)

__device__ __forceinline__ float us2f(unsigned short u) {
    unsigned int v = ((unsigned int)u) << 16;
    return __uint_as_float(v);
}
// float -> bf16 bits, round-to-nearest-even (pure bit ops)
__device__ __forceinline__ unsigned short f2us(float f) {
    unsigned int b = __float_as_uint(f);
    unsigned int r = (b + 0x7FFFu + ((b >> 16) & 1u)) >> 16;
    return (unsigned short)r;
}

// ---- dtype detector, wave-parallel ----------------------------------------
__global__ void detect_kernel(const unsigned short* __restrict__ xraw,
                              float* __restrict__ ws) {
    int l = threadIdx.x;  // 64 threads, one wave
    float v0 = us2f(xraw[l]);
    float v1 = us2f(xraw[64 + l]);
    int big = (!(fabsf(v0) < 1e4f)) || (!(fabsf(v1) < 1e4f));
    #pragma unroll
    for (int m = 32; m >= 1; m >>= 1) big |= __shfl_xor(big, m, 64);
    if (l == 0) ws[97] = big ? 0.0f : 1.0f;
}

// ---- zero int/float words --------------------------------------------------
__global__ void zero_kernel(float* __restrict__ p, long n) {
    long i = (long)blockIdx.x * blockDim.x + threadIdx.x;
    long stride = (long)gridDim.x * blockDim.x;
    for (; i < n; i += stride) p[i] = 0.0f;
}

// ---- hyp_bias = proj(expmap0(bias)), wave-parallel (round-4 proven form) --
__global__ void hb_kernel(const void* __restrict__ bias,
                          float* __restrict__ ws) {
    int l = threadIdx.x;  // 64 threads, one wave
    bool isb = ws[97] != 0.0f;
    float b0 = isb ? us2f(((const unsigned short*)bias)[l])
                   : ((const float*)bias)[l];
    float b1 = 0.0f;
    if (l < 32)
        b1 = isb ? us2f(((const unsigned short*)bias)[64 + l])
                 : ((const float*)bias)[64 + l];
    float n2 = b0 * b0 + b1 * b1;
    #pragma unroll
    for (int m = 32; m >= 1; m >>= 1) n2 += __shfl_xor(n2, m, 64);
    float bn = fmaxf(sqrtf(n2), EPS15);
    float ef = tanhf(bn) / bn;
    float hn = ef * sqrtf(n2);  // norm of expmap0(bias)
    float s = (hn > MAXN) ? MAXN / fmaxf(hn, EPS15) : 1.0f;
    ws[l] = s * ef * b0;
    if (l < 32) ws[64 + l] = s * ef * b1;
    if (l == 0) { float v = s * hn; ws[96] = v * v; }
}

// ---- degree histogram ------------------------------------------------------
__global__ void hist_kernel(const int* __restrict__ erow,
                            int* __restrict__ deg, int E) {
    int e = blockIdx.x * blockDim.x + threadIdx.x;
    if (e < E) atomicAdd(&deg[erow[e]], 1);
}

// ---- hierarchical scan: phase A (per-block sums of 1024 elems) ------------
__global__ void scanA_kernel(const int* __restrict__ deg,
                             int* __restrict__ bsum, int N) {
    int t = threadIdx.x, lane = t & 63, wv = t >> 6;
    int base = blockIdx.x * 1024 + t * 4;
    int v = 0;
    #pragma unroll
    for (int j = 0; j < 4; j++) {
        int i = base + j;
        if (i < N) v += deg[i];
    }
    #pragma unroll
    for (int m = 32; m >= 1; m >>= 1) v += __shfl_xor(v, m, 64);
    __shared__ int wsum[4];
    if (lane == 0) wsum[wv] = v;
    __syncthreads();
    if (t == 0) bsum[blockIdx.x] = wsum[0] + wsum[1] + wsum[2] + wsum[3];
}

// ---- phase B: one wave scans the block sums -------------------------------
__global__ void scanB_kernel(const int* __restrict__ bsum,
                             int* __restrict__ boff,
                             int* __restrict__ offN, int nb) {
    int lane = threadIdx.x;  // 64 threads
    int running = 0;
    for (int b = 0; b < nb; b += 64) {
        int i = b + lane;
        int v = (i < nb) ? bsum[i] : 0;
        int s = v;
        #pragma unroll
        for (int d = 1; d < 64; d <<= 1) {
            int t = __shfl_up(s, d, 64);
            if (lane >= d) s += t;
        }
        if (i < nb) boff[i] = running + s - v;
        running += __shfl(s, 63, 64);
    }
    if (lane == 0) *offN = running;
}

// ---- phase C: block-local exclusive scan + block offset -------------------
__global__ void scanC_kernel(const int* __restrict__ deg,
                             const int* __restrict__ boff,
                             int* __restrict__ off, int* __restrict__ pos,
                             int N) {
    int t = threadIdx.x, lane = t & 63, wv = t >> 6;
    int base = blockIdx.x * 1024 + t * 4;
    int v[4]; int s = 0;
    #pragma unroll
    for (int j = 0; j < 4; j++) {
        int i = base + j;
        v[j] = (i < N) ? deg[i] : 0;
        s += v[j];
    }
    int sc = s;
    #pragma unroll
    for (int d = 1; d < 64; d <<= 1) {
        int tt = __shfl_up(sc, d, 64);
        if (lane >= d) sc += tt;
    }
    __shared__ int wsum[4];
    if (lane == 63) wsum[wv] = sc;
    __syncthreads();
    int wo = 0;
    for (int k = 0; k < wv; k++) wo += wsum[k];
    int excl = boff[blockIdx.x] + wo + (sc - s);
    #pragma unroll
    for (int j = 0; j < 4; j++) {
        int i = base + j;
        if (i < N) { off[i] = excl; pos[i] = excl; }
        excl += v[j];
    }
}

// ---- CSR fill: einfo[slot] = {col, w_bits} --------------------------------
__global__ void fill_kernel(const void* __restrict__ ew,
                            const int* __restrict__ erow,
                            const int* __restrict__ ecol,
                            float* __restrict__ ws,
                            int* __restrict__ pos,
                            uint2* __restrict__ einfo, int E) {
    int e = blockIdx.x * blockDim.x + threadIdx.x;
    if (e >= E) return;
    const bool isb = ws[97] != 0.0f;
    float w = isb ? us2f(((const unsigned short*)ew)[e]) : ((const float*)ew)[e];
    int p = atomicAdd(&pos[erow[e]], 1);
    uint2 v; v.x = (unsigned)ecol[e]; v.y = __float_as_uint(w);
    einfo[p] = v;
}

// ---- HypLinear v3: MFMA GEMM + scalar mobius tail (round-7 proven) --------
__global__ void hyplinear_kernel(const void* __restrict__ x,
                                 const void* __restrict__ wgt,
                                 float* __restrict__ ws,
                                 unsigned short* __restrict__ xtb, int N) {
    const int lane = threadIdx.x & 63;
    const int wv = threadIdx.x >> 6;
    const int mrow = lane & 15;
    const int quad = lane >> 4;
    const int r0 = (blockIdx.x * 4 + wv) * 16;
    if (r0 >= N) return;
    const bool isb = ws[97] != 0.0f;

    float hbl[6];
    #pragma unroll
    for (int f = 0; f < 6; f++) hbl[f] = ws[mrow + 16 * f];
    const float hb2 = ws[96];

    int xr = r0 + mrow; if (xr >= N) xr = N - 1;
    short8 afrag[8];
    if (isb) {
        const unsigned short* xrow = (const unsigned short*)x + (size_t)xr * DIN + quad * 8;
        #pragma unroll
        for (int kt = 0; kt < 8; kt++)
            afrag[kt] = *(const short8*)(xrow + kt * 32);
    } else {
        const float* xrow = (const float*)x + (size_t)xr * DIN + quad * 8;
        #pragma unroll
        for (int kt = 0; kt < 8; kt++) {
            short8 a;
            #pragma unroll
            for (int j = 0; j < 8; j++) a[j] = (short)f2us(xrow[kt * 32 + j]);
            afrag[kt] = a;
        }
    }

    float xn2p = 0.f;
    #pragma unroll
    for (int kt = 0; kt < 8; kt++)
        #pragma unroll
        for (int j = 0; j < 8; j++) {
            float v = us2f((unsigned short)afrag[kt][j]);
            xn2p = fmaf(v, v, xn2p);
        }
    xn2p += __shfl_xor(xn2p, 16, 64);
    xn2p += __shfl_xor(xn2p, 32, 64);

    floatx4 acc[6];
    #pragma unroll
    for (int f = 0; f < 6; f++) acc[f] = (floatx4){0.f, 0.f, 0.f, 0.f};
    #pragma unroll
    for (int f = 0; f < 6; f++) {
        if (isb) {
            const unsigned short* wrow = (const unsigned short*)wgt + (size_t)(16 * f + mrow) * DIN + quad * 8;
            #pragma unroll
            for (int kt = 0; kt < 8; kt++) {
                short8 b = *(const short8*)(wrow + kt * 32);
                acc[f] = __builtin_amdgcn_mfma_f32_16x16x32_bf16(afrag[kt], b, acc[f], 0, 0, 0);
            }
        } else {
            const float* wrow = (const float*)wgt + (size_t)(16 * f + mrow) * DIN + quad * 8;
            #pragma unroll
            for (int kt = 0; kt < 8; kt++) {
                short8 b;
                #pragma unroll
                for (int j = 0; j < 8; j++) b[j] = (short)f2us(wrow[kt * 32 + j]);
                acc[f] = __builtin_amdgcn_mfma_f32_16x16x32_bf16(afrag[kt], b, acc[f], 0, 0, 0);
            }
        }
    }

    float mxn2[4], dmh[4];
    #pragma unroll
    for (int reg = 0; reg < 4; reg++) {
        float a2 = 0.f, ad = 0.f;
        #pragma unroll
        for (int f = 0; f < 6; f++) {
            float v = acc[f][reg];
            a2 = fmaf(v, v, a2);
            ad = fmaf(v, hbl[f], ad);
        }
        mxn2[reg] = a2; dmh[reg] = ad;
    }
    #pragma unroll
    for (int m = 8; m >= 1; m >>= 1)
        #pragma unroll
        for (int reg = 0; reg < 4; reg++) {
            mxn2[reg] += __shfl_xor(mxn2[reg], m, 64);
            dmh[reg]  += __shfl_xor(dmh[reg],  m, 64);
        }

    int sel = mrow & 3;
    float xn2  = __shfl(xn2p, quad * 4 + sel, 64);
    float wmx2 = mxn2[sel], wdmh = dmh[sel];

    float xn  = fmaxf(sqrtf(xn2), EPS15);
    float mxn = fmaxf(sqrtf(wmx2), EPS15);
    float g   = (mxn / xn) * atanhf(fminf(xn, ATC));
    float tg  = tanhf(g);
    float rs0 = tg / mxn;
    float rn  = rs0 * sqrtf(wmx2);
    float s1  = (rn > MAXN) ? MAXN / fmaxf(rn, EPS15) : 1.0f;
    float al  = s1 * rs0;
    float x2  = al * al * wmx2;
    float xy  = al * wdmh;
    float cA  = 1.0f + 2.0f * xy + hb2;
    float cB  = 1.0f - x2;
    float den = fmaxf(1.0f + 2.0f * xy + x2 * hb2, EPS15);
    float p   = cA * al / den;
    float qq  = cB / den;
    float o2  = p*p*wmx2 + 2.0f*p*qq*wdmh + qq*qq*hb2;
    float on  = sqrtf(fmaxf(o2, 0.0f));
    float s2  = (on > MAXN) ? MAXN / fmaxf(on, EPS15) : 1.0f;
    float pn  = fmaxf(s2 * on, EPS15);
    float F   = (atanhf(fminf(pn, ATC)) / pn) * s2;
    float Fp_m = F * p, Fq_m = F * qq;

    float Fp[4], Fq[4];
    #pragma unroll
    for (int reg = 0; reg < 4; reg++) {
        Fp[reg] = __shfl(Fp_m, quad * 16 + reg, 64);
        Fq[reg] = __shfl(Fq_m, quad * 16 + reg, 64);
    }

    #pragma unroll
    for (int reg = 0; reg < 4; reg++) {
        int row = r0 + quad * 4 + reg;
        if (row < N) {
            size_t base = (size_t)row * DOUT + mrow;
            #pragma unroll
            for (int f = 0; f < 6; f++)
                xtb[base + 16 * f] = f2us(fmaf(Fp[reg], acc[f][reg], Fq[reg] * hbl[f]));
        }
    }
}

// ---- aggregation v2: coalesced einfo preload + 4-edge unroll --------------
__global__ void agg_kernel(const unsigned short* __restrict__ xtb,
                           const uint2* __restrict__ einfo,
                           const int* __restrict__ off,
                           float* __restrict__ ws,
                           void* __restrict__ out, int N) {
    int wv = threadIdx.x >> 6, lane = threadIdx.x & 63;
    int node = blockIdx.x * 4 + wv;
    if (node >= N) return;
    const bool isb = ws[97] != 0.0f;

    int s = off[node], e2 = off[node + 1];
    float a0[4] = {0.f, 0.f, 0.f, 0.f};
    float a1[4] = {0.f, 0.f, 0.f, 0.f};

    for (int cs = s; cs < e2; cs += 64) {
        int cnt = e2 - cs; if (cnt > 64) cnt = 64;
        // coalesced preload of this chunk's edge info
        uint2 my; my.x = 0u; my.y = 0u;
        if (cs + lane < e2) my = einfo[cs + lane];

        int j = 0;
        for (; j + 4 <= cnt; j += 4) {
            const unsigned short* sp[4];
            float w[4];
            #pragma unroll
            for (int k = 0; k < 4; k++) {
                int   c = __shfl((int)my.x, j + k, 64);
                w[k]    = __uint_as_float(__shfl((int)my.y, j + k, 64));
                sp[k]   = xtb + (size_t)c * DOUT;
            }
            float v0[4], v1[4];
            #pragma unroll
            for (int k = 0; k < 4; k++) v0[k] = us2f(sp[k][lane]);
            #pragma unroll
            for (int k = 0; k < 4; k++)
                v1[k] = (lane < 32) ? us2f(sp[k][64 + lane]) : 0.f;
            #pragma unroll
            for (int k = 0; k < 4; k++) {
                a0[k] = fmaf(w[k], v0[k], a0[k]);
                a1[k] = fmaf(w[k], v1[k], a1[k]);
            }
        }
        for (; j < cnt; j++) {
            int   c = __shfl((int)my.x, j, 64);
            float w = __uint_as_float(__shfl((int)my.y, j, 64));
            const unsigned short* sp = xtb + (size_t)c * DOUT;
            a0[0] = fmaf(w, us2f(sp[lane]), a0[0]);
            if (lane < 32) a1[0] = fmaf(w, us2f(sp[64 + lane]), a1[0]);
        }
    }
    float acc0 = (a0[0] + a0[1]) + (a0[2] + a0[3]);
    float acc1 = (a1[0] + a1[1]) + (a1[2] + a1[3]);

    // fused final chain: proj(expmap0(relu(logmap0(proj(expmap0(.))))))
    float u0 = acc0, u1 = acc1;
    float n2 = u0*u0 + u1*u1;
    #pragma unroll
    for (int m = 32; m >= 1; m >>= 1) n2 += __shfl_xor(n2, m, 64);
    float un = fmaxf(sqrtf(n2), EPS15);
    float ef = tanhf(un) / un;
    float p0 = ef * u0, p1 = ef * u1;
    float pnrm = ef * sqrtf(n2);
    float sc = (pnrm > MAXN) ? MAXN / fmaxf(pnrm, EPS15) : 1.0f;
    p0 *= sc; p1 *= sc; pnrm *= sc;
    float pncl = fmaxf(pnrm, EPS15);
    float lf = atanhf(fminf(pncl, ATC)) / pncl;
    float t0 = fmaxf(lf * p0, 0.0f), t1 = fmaxf(lf * p1, 0.0f);
    float tn2 = t0*t0 + t1*t1;
    #pragma unroll
    for (int m = 32; m >= 1; m >>= 1) tn2 += __shfl_xor(tn2, m, 64);
    float tn = fmaxf(sqrtf(tn2), EPS15);
    float ef2 = tanhf(tn) / tn;
    float en = ef2 * sqrtf(tn2);
    float s2 = (en > MAXN) ? MAXN / fmaxf(en, EPS15) : 1.0f;
    float scale = s2 * ef2;

    size_t ob = (size_t)node * DOUT;
    if (isb) {
        ((unsigned short*)out)[ob + lane] = f2us(scale * t0);
        if (lane < 32)
            ((unsigned short*)out)[ob + 64 + lane] = f2us(scale * t1);
    } else {
        ((float*)out)[ob + lane] = scale * t0;
        if (lane < 32)
            ((float*)out)[ob + 64 + lane] = scale * t1;
    }
}

extern "C" void kernel_launch(void* const* d_in, const int* in_sizes, int n_in,
                              void* d_out, int out_size, void* d_ws, size_t ws_size,
                              hipStream_t stream) {
    const void* x    = d_in[0];
    const void* wgt  = d_in[1];
    const void* bias = d_in[2];
    const void* ew   = d_in[3];
    const int* erow  = (const int*)d_in[4];
    const int* ecol  = (const int*)d_in[5];

    int N = out_size / DOUT;      // 50000
    int E = in_sizes[4];          // 800000
    size_t nd = (size_t)N * DOUT;
    int nb = (N + 1023) / 1024;   // scan blocks (49)

    float* wsf = (float*)d_ws;
    uint2* einfo        = (uint2*)(wsf + 128);
    unsigned short* xtb = (unsigned short*)(wsf + 128 + 2 * (size_t)E);
    int* deg            = (int*)(xtb + nd);
    int* off            = deg + N;
    int* pos            = off + N + 1;
    int* bsum           = pos + N;
    int* boff           = bsum + 64;

    detect_kernel<<<1, 64, 0, stream>>>((const unsigned short*)x, wsf);
    zero_kernel<<<128, 256, 0, stream>>>((float*)deg, N);
    hb_kernel<<<1, 64, 0, stream>>>(bias, wsf);
    hist_kernel<<<(E + 255) / 256, 256, 0, stream>>>(erow, deg, E);
    scanA_kernel<<<nb, 256, 0, stream>>>(deg, bsum, N);
    scanB_kernel<<<1, 64, 0, stream>>>(bsum, boff, off + N, nb);
    scanC_kernel<<<nb, 256, 0, stream>>>(deg, boff, off, pos, N);
    fill_kernel<<<(E + 255) / 256, 256, 0, stream>>>(ew, erow, ecol, wsf, pos, einfo, E);
    hyplinear_kernel<<<(N + 63) / 64, 256, 0, stream>>>(x, wgt, wsf, xtb, N);
    agg_kernel<<<(N + 3) / 4, 256, 0, stream>>>(xtb, einfo, off, wsf, d_out, N);
}

// Round 9
// 241.172 us; speedup vs baseline: 3.7907x; 1.2290x over previous
//
#include <hip/hip_runtime.h>

// HGCNConv on MI355X. Round 9:
//  (a) hyplinear: W staged in LDS in MFMA-fragment-swizzled order ->
//      conflict-free ds_read_b128 in the K-loop (was 48 L2 round-trips/wave)
//  (b) agg: xt gathered as 48-lane dword (2 packed bf16/lane, 1 instr/edge)
//      with 8-edge unroll
//  (c) detect+hb fused into init_kernel
// Everything else byte-identical to the round-8 PASS.
//
// ws word layout:
//   [0..95] hyp_bias, [96] ||hb||^2, [97] dtype flag (1=bf16, 0=f32)
//   [128 .. 128+2E)                einfo: uint2 {col, w_bits} per CSR slot
//   then  xt bf16 [N*96 ushorts]   (logmap0 output of HypLinear)
//   then  deg[N] int, off[N+1] int, pos[N] int, bsum[64], boff[64]

typedef __attribute__((ext_vector_type(8))) short short8;
typedef __attribute__((ext_vector_type(4))) float floatx4;

#define DIN 256
#define DOUT 96
#define MAXN 0.996f         // (1 - 4e-3)/sqrt(c)
#define EPS15 1e-15f
#define ATC (1.0f - 1e-7f)

__device__ __forceinline__ float us2f(unsigned short u) {
    unsigned int v = ((unsigned int)u) << 16;
    return __uint_as_float(v);
}
// float -> bf16 bits, round-to-nearest-even (pure bit ops)
__device__ __forceinline__ unsigned short f2us(float f) {
    unsigned int b = __float_as_uint(f);
    unsigned int r = (b + 0x7FFFu + ((b >> 16) & 1u)) >> 16;
    return (unsigned short)r;
}

// ---- init: dtype detect + hyp_bias = proj(expmap0(bias)), one wave --------
__global__ void init_kernel(const unsigned short* __restrict__ xraw,
                            const void* __restrict__ bias,
                            float* __restrict__ ws) {
    int l = threadIdx.x;  // 64 threads, one wave
    float v0 = us2f(xraw[l]);
    float v1 = us2f(xraw[64 + l]);
    int big = (!(fabsf(v0) < 1e4f)) || (!(fabsf(v1) < 1e4f));
    #pragma unroll
    for (int m = 32; m >= 1; m >>= 1) big |= __shfl_xor(big, m, 64);
    bool isb = !big;
    if (l == 0) ws[97] = isb ? 1.0f : 0.0f;

    float b0 = isb ? us2f(((const unsigned short*)bias)[l])
                   : ((const float*)bias)[l];
    float b1 = 0.0f;
    if (l < 32)
        b1 = isb ? us2f(((const unsigned short*)bias)[64 + l])
                 : ((const float*)bias)[64 + l];
    float n2 = b0 * b0 + b1 * b1;
    #pragma unroll
    for (int m = 32; m >= 1; m >>= 1) n2 += __shfl_xor(n2, m, 64);
    float bn = fmaxf(sqrtf(n2), EPS15);
    float ef = tanhf(bn) / bn;
    float hn = ef * sqrtf(n2);
    float s = (hn > MAXN) ? MAXN / fmaxf(hn, EPS15) : 1.0f;
    ws[l] = s * ef * b0;
    if (l < 32) ws[64 + l] = s * ef * b1;
    if (l == 0) { float v = s * hn; ws[96] = v * v; }
}

// ---- zero int/float words --------------------------------------------------
__global__ void zero_kernel(float* __restrict__ p, long n) {
    long i = (long)blockIdx.x * blockDim.x + threadIdx.x;
    long stride = (long)gridDim.x * blockDim.x;
    for (; i < n; i += stride) p[i] = 0.0f;
}

// ---- degree histogram ------------------------------------------------------
__global__ void hist_kernel(const int* __restrict__ erow,
                            int* __restrict__ deg, int E) {
    int e = blockIdx.x * blockDim.x + threadIdx.x;
    if (e < E) atomicAdd(&deg[erow[e]], 1);
}

// ---- hierarchical scan: phase A (per-block sums of 1024 elems) ------------
__global__ void scanA_kernel(const int* __restrict__ deg,
                             int* __restrict__ bsum, int N) {
    int t = threadIdx.x, lane = t & 63, wv = t >> 6;
    int base = blockIdx.x * 1024 + t * 4;
    int v = 0;
    #pragma unroll
    for (int j = 0; j < 4; j++) {
        int i = base + j;
        if (i < N) v += deg[i];
    }
    #pragma unroll
    for (int m = 32; m >= 1; m >>= 1) v += __shfl_xor(v, m, 64);
    __shared__ int wsum[4];
    if (lane == 0) wsum[wv] = v;
    __syncthreads();
    if (t == 0) bsum[blockIdx.x] = wsum[0] + wsum[1] + wsum[2] + wsum[3];
}

// ---- phase B: one wave scans the block sums -------------------------------
__global__ void scanB_kernel(const int* __restrict__ bsum,
                             int* __restrict__ boff,
                             int* __restrict__ offN, int nb) {
    int lane = threadIdx.x;  // 64 threads
    int running = 0;
    for (int b = 0; b < nb; b += 64) {
        int i = b + lane;
        int v = (i < nb) ? bsum[i] : 0;
        int s = v;
        #pragma unroll
        for (int d = 1; d < 64; d <<= 1) {
            int t = __shfl_up(s, d, 64);
            if (lane >= d) s += t;
        }
        if (i < nb) boff[i] = running + s - v;
        running += __shfl(s, 63, 64);
    }
    if (lane == 0) *offN = running;
}

// ---- phase C: block-local exclusive scan + block offset -------------------
__global__ void scanC_kernel(const int* __restrict__ deg,
                             const int* __restrict__ boff,
                             int* __restrict__ off, int* __restrict__ pos,
                             int N) {
    int t = threadIdx.x, lane = t & 63, wv = t >> 6;
    int base = blockIdx.x * 1024 + t * 4;
    int v[4]; int s = 0;
    #pragma unroll
    for (int j = 0; j < 4; j++) {
        int i = base + j;
        v[j] = (i < N) ? deg[i] : 0;
        s += v[j];
    }
    int sc = s;
    #pragma unroll
    for (int d = 1; d < 64; d <<= 1) {
        int tt = __shfl_up(sc, d, 64);
        if (lane >= d) sc += tt;
    }
    __shared__ int wsum[4];
    if (lane == 63) wsum[wv] = sc;
    __syncthreads();
    int wo = 0;
    for (int k = 0; k < wv; k++) wo += wsum[k];
    int excl = boff[blockIdx.x] + wo + (sc - s);
    #pragma unroll
    for (int j = 0; j < 4; j++) {
        int i = base + j;
        if (i < N) { off[i] = excl; pos[i] = excl; }
        excl += v[j];
    }
}

// ---- CSR fill: einfo[slot] = {col, w_bits} --------------------------------
__global__ void fill_kernel(const void* __restrict__ ew,
                            const int* __restrict__ erow,
                            const int* __restrict__ ecol,
                            float* __restrict__ ws,
                            int* __restrict__ pos,
                            uint2* __restrict__ einfo, int E) {
    int e = blockIdx.x * blockDim.x + threadIdx.x;
    if (e >= E) return;
    const bool isb = ws[97] != 0.0f;
    float w = isb ? us2f(((const unsigned short*)ew)[e]) : ((const float*)ew)[e];
    int p = atomicAdd(&pos[erow[e]], 1);
    uint2 v; v.x = (unsigned)ecol[e]; v.y = __float_as_uint(w);
    einfo[p] = v;
}

// ---- HypLinear v4: MFMA GEMM, W staged in LDS (fragment-swizzled) ---------
// Block = 256 (4 waves), 64 rows. W (96x256 bf16 = 48 KB) staged once in LDS
// at chunk index ((f*8+kt)*64 + lane) so the K-loop is conflict-free
// ds_read_b128. x fragments load straight from global (HBM, streamed once).
__global__ void hyplinear_kernel(const void* __restrict__ x,
                                 const void* __restrict__ wgt,
                                 float* __restrict__ ws,
                                 unsigned short* __restrict__ xtb, int N) {
    __shared__ uint4 Wl[3072];   // 48 KB

    const int t = threadIdx.x;
    const int lane = t & 63;
    const int wv = t >> 6;
    const int mrow = lane & 15;
    const int quad = lane >> 4;
    const bool isb = ws[97] != 0.0f;

    // stage W swizzled: global chunk g = c*32 + j (c=16f+mr, j=kt*4+q)
    // -> Wl[(f*8+kt)*64 + q*16 + mr]
    if (isb) {
        const uint4* wg = (const uint4*)wgt;
        #pragma unroll
        for (int i = 0; i < 12; i++) {
            int g = t + 256 * i;            // 3072 chunks
            int c = g >> 5, j = g & 31;
            int f = c >> 4, mr = c & 15;
            int kt = j >> 2, q = j & 3;
            Wl[(f * 8 + kt) * 64 + q * 16 + mr] = wg[g];
        }
    } else {
        const float* wgf = (const float*)wgt;
        #pragma unroll
        for (int i = 0; i < 12; i++) {
            int g = t + 256 * i;
            int c = g >> 5, j = g & 31;
            int f = c >> 4, mr = c & 15;
            int kt = j >> 2, q = j & 3;
            const float* src = wgf + (size_t)c * DIN + j * 8;
            unsigned short tmp[8];
            #pragma unroll
            for (int z = 0; z < 8; z++) tmp[z] = f2us(src[z]);
            Wl[(f * 8 + kt) * 64 + q * 16 + mr] = *(const uint4*)tmp;
        }
    }
    __syncthreads();

    const int r0 = (blockIdx.x * 4 + wv) * 16;
    if (r0 >= N) return;

    float hbl[6];
    #pragma unroll
    for (int f = 0; f < 6; f++) hbl[f] = ws[mrow + 16 * f];
    const float hb2 = ws[96];

    int xr = r0 + mrow; if (xr >= N) xr = N - 1;
    short8 afrag[8];
    if (isb) {
        const unsigned short* xrow = (const unsigned short*)x + (size_t)xr * DIN + quad * 8;
        #pragma unroll
        for (int kt = 0; kt < 8; kt++)
            afrag[kt] = *(const short8*)(xrow + kt * 32);
    } else {
        const float* xrow = (const float*)x + (size_t)xr * DIN + quad * 8;
        #pragma unroll
        for (int kt = 0; kt < 8; kt++) {
            short8 a;
            #pragma unroll
            for (int j = 0; j < 8; j++) a[j] = (short)f2us(xrow[kt * 32 + j]);
            afrag[kt] = a;
        }
    }

    float xn2p = 0.f;
    #pragma unroll
    for (int kt = 0; kt < 8; kt++)
        #pragma unroll
        for (int j = 0; j < 8; j++) {
            float v = us2f((unsigned short)afrag[kt][j]);
            xn2p = fmaf(v, v, xn2p);
        }
    xn2p += __shfl_xor(xn2p, 16, 64);
    xn2p += __shfl_xor(xn2p, 32, 64);

    floatx4 acc[6];
    #pragma unroll
    for (int f = 0; f < 6; f++) acc[f] = (floatx4){0.f, 0.f, 0.f, 0.f};
    #pragma unroll
    for (int f = 0; f < 6; f++) {
        #pragma unroll
        for (int kt = 0; kt < 8; kt++) {
            uint4 bw = Wl[(f * 8 + kt) * 64 + lane];
            short8 b = *(const short8*)&bw;
            acc[f] = __builtin_amdgcn_mfma_f32_16x16x32_bf16(afrag[kt], b, acc[f], 0, 0, 0);
        }
    }
    // D layout (m89-verified): acc[f][reg] = mx[row = quad*4+reg][col = mrow + 16f]

    float mxn2[4], dmh[4];
    #pragma unroll
    for (int reg = 0; reg < 4; reg++) {
        float a2 = 0.f, ad = 0.f;
        #pragma unroll
        for (int f = 0; f < 6; f++) {
            float v = acc[f][reg];
            a2 = fmaf(v, v, a2);
            ad = fmaf(v, hbl[f], ad);
        }
        mxn2[reg] = a2; dmh[reg] = ad;
    }
    #pragma unroll
    for (int m = 8; m >= 1; m >>= 1)
        #pragma unroll
        for (int reg = 0; reg < 4; reg++) {
            mxn2[reg] += __shfl_xor(mxn2[reg], m, 64);
            dmh[reg]  += __shfl_xor(dmh[reg],  m, 64);
        }

    int sel = mrow & 3;
    float xn2  = __shfl(xn2p, quad * 4 + sel, 64);
    float wmx2 = mxn2[sel], wdmh = dmh[sel];

    float xn  = fmaxf(sqrtf(xn2), EPS15);
    float mxn = fmaxf(sqrtf(wmx2), EPS15);
    float g   = (mxn / xn) * atanhf(fminf(xn, ATC));
    float tg  = tanhf(g);
    float rs0 = tg / mxn;
    float rn  = rs0 * sqrtf(wmx2);
    float s1  = (rn > MAXN) ? MAXN / fmaxf(rn, EPS15) : 1.0f;
    float al  = s1 * rs0;
    float x2  = al * al * wmx2;
    float xy  = al * wdmh;
    float cA  = 1.0f + 2.0f * xy + hb2;
    float cB  = 1.0f - x2;
    float den = fmaxf(1.0f + 2.0f * xy + x2 * hb2, EPS15);
    float p   = cA * al / den;
    float qq  = cB / den;
    float o2  = p*p*wmx2 + 2.0f*p*qq*wdmh + qq*qq*hb2;
    float on  = sqrtf(fmaxf(o2, 0.0f));
    float s2  = (on > MAXN) ? MAXN / fmaxf(on, EPS15) : 1.0f;
    float pn  = fmaxf(s2 * on, EPS15);
    float F   = (atanhf(fminf(pn, ATC)) / pn) * s2;
    float Fp_m = F * p, Fq_m = F * qq;

    float Fp[4], Fq[4];
    #pragma unroll
    for (int reg = 0; reg < 4; reg++) {
        Fp[reg] = __shfl(Fp_m, quad * 16 + reg, 64);
        Fq[reg] = __shfl(Fq_m, quad * 16 + reg, 64);
    }

    #pragma unroll
    for (int reg = 0; reg < 4; reg++) {
        int row = r0 + quad * 4 + reg;
        if (row < N) {
            size_t base = (size_t)row * DOUT + mrow;
            #pragma unroll
            for (int f = 0; f < 6; f++)
                xtb[base + 16 * f] = f2us(fmaf(Fp[reg], acc[f][reg], Fq[reg] * hbl[f]));
        }
    }
}

// ---- aggregation v3: dword gather (2 bf16/lane), 8-edge unroll ------------
__global__ void agg_kernel(const unsigned short* __restrict__ xtb,
                           const uint2* __restrict__ einfo,
                           const int* __restrict__ off,
                           float* __restrict__ ws,
                           void* __restrict__ out, int N) {
    int wv = threadIdx.x >> 6, lane = threadIdx.x & 63;
    int node = blockIdx.x * 4 + wv;
    if (node >= N) return;
    const bool isb = ws[97] != 0.0f;
    const bool act = lane < 48;   // lane l handles features 2l, 2l+1

    int s = off[node], e2 = off[node + 1];
    float acc0 = 0.f, acc1 = 0.f;

    for (int cs = s; cs < e2; cs += 64) {
        int cnt = e2 - cs; if (cnt > 64) cnt = 64;
        uint2 my; my.x = 0u; my.y = 0u;
        if (cs + lane < e2) my = einfo[cs + lane];

        int j = 0;
        for (; j + 8 <= cnt; j += 8) {
            float w[8]; const unsigned int* sp[8];
            #pragma unroll
            for (int k = 0; k < 8; k++) {
                int c = __shfl((int)my.x, j + k, 64);
                w[k] = __uint_as_float(__shfl((int)my.y, j + k, 64));
                sp[k] = (const unsigned int*)(xtb + (size_t)c * DOUT);
            }
            unsigned int u[8];
            #pragma unroll
            for (int k = 0; k < 8; k++) u[k] = act ? sp[k][lane] : 0u;
            #pragma unroll
            for (int k = 0; k < 8; k++) {
                acc0 = fmaf(w[k], __uint_as_float(u[k] << 16), acc0);
                acc1 = fmaf(w[k], __uint_as_float(u[k] & 0xFFFF0000u), acc1);
            }
        }
        for (; j < cnt; j++) {
            int c = __shfl((int)my.x, j, 64);
            float w = __uint_as_float(__shfl((int)my.y, j, 64));
            unsigned int u = act ? ((const unsigned int*)(xtb + (size_t)c * DOUT))[lane] : 0u;
            acc0 = fmaf(w, __uint_as_float(u << 16), acc0);
            acc1 = fmaf(w, __uint_as_float(u & 0xFFFF0000u), acc1);
        }
    }

    // fused final chain: proj(expmap0(relu(logmap0(proj(expmap0(.))))))
    float u0 = acc0, u1 = acc1;
    float n2 = u0*u0 + u1*u1;
    #pragma unroll
    for (int m = 32; m >= 1; m >>= 1) n2 += __shfl_xor(n2, m, 64);
    float un = fmaxf(sqrtf(n2), EPS15);
    float ef = tanhf(un) / un;
    float p0 = ef * u0, p1 = ef * u1;
    float pnrm = ef * sqrtf(n2);
    float sc = (pnrm > MAXN) ? MAXN / fmaxf(pnrm, EPS15) : 1.0f;
    p0 *= sc; p1 *= sc; pnrm *= sc;
    float pncl = fmaxf(pnrm, EPS15);
    float lf = atanhf(fminf(pncl, ATC)) / pncl;
    float t0 = fmaxf(lf * p0, 0.0f), t1 = fmaxf(lf * p1, 0.0f);
    float tn2 = t0*t0 + t1*t1;
    #pragma unroll
    for (int m = 32; m >= 1; m >>= 1) tn2 += __shfl_xor(tn2, m, 64);
    float tn = fmaxf(sqrtf(tn2), EPS15);
    float ef2 = tanhf(tn) / tn;
    float en = ef2 * sqrtf(tn2);
    float s2 = (en > MAXN) ? MAXN / fmaxf(en, EPS15) : 1.0f;
    float scale = s2 * ef2;
    float v0 = scale * t0, v1 = scale * t1;

    if (act) {
        if (isb) {
            unsigned int pk = ((unsigned int)f2us(v1) << 16) | (unsigned int)f2us(v0);
            ((unsigned int*)((unsigned short*)out + (size_t)node * DOUT))[lane] = pk;
        } else {
            float2 fv; fv.x = v0; fv.y = v1;
            ((float2*)((float*)out + (size_t)node * DOUT))[lane] = fv;
        }
    }
}

extern "C" void kernel_launch(void* const* d_in, const int* in_sizes, int n_in,
                              void* d_out, int out_size, void* d_ws, size_t ws_size,
                              hipStream_t stream) {
    const void* x    = d_in[0];
    const void* wgt  = d_in[1];
    const void* bias = d_in[2];
    const void* ew   = d_in[3];
    const int* erow  = (const int*)d_in[4];
    const int* ecol  = (const int*)d_in[5];

    int N = out_size / DOUT;      // 50000
    int E = in_sizes[4];          // 800000
    size_t nd = (size_t)N * DOUT;
    int nb = (N + 1023) / 1024;   // scan blocks (49)

    float* wsf = (float*)d_ws;
    uint2* einfo        = (uint2*)(wsf + 128);
    unsigned short* xtb = (unsigned short*)(wsf + 128 + 2 * (size_t)E);
    int* deg            = (int*)(xtb + nd);
    int* off            = deg + N;
    int* pos            = off + N + 1;
    int* bsum           = pos + N;
    int* boff           = bsum + 64;

    init_kernel<<<1, 64, 0, stream>>>((const unsigned short*)x, bias, wsf);
    zero_kernel<<<128, 256, 0, stream>>>((float*)deg, N);
    hist_kernel<<<(E + 255) / 256, 256, 0, stream>>>(erow, deg, E);
    scanA_kernel<<<nb, 256, 0, stream>>>(deg, bsum, N);
    scanB_kernel<<<1, 64, 0, stream>>>(bsum, boff, off + N, nb);
    scanC_kernel<<<nb, 256, 0, stream>>>(deg, boff, off, pos, N);
    fill_kernel<<<(E + 255) / 256, 256, 0, stream>>>(ew, erow, ecol, wsf, pos, einfo, E);
    hyplinear_kernel<<<(N + 63) / 64, 256, 0, stream>>>(x, wgt, wsf, xtb, N);
    agg_kernel<<<(N + 3) / 4, 256, 0, stream>>>(xtb, einfo, off, wsf, d_out, N);
}